// Round 1
// baseline (182.455 us; speedup 1.0000x reference)
//
#include <hip/hip_runtime.h>

// ExtractTsFeatures: x (512, 1024, 32) fp32 -> out (512, 32, 30) fp32.
// K0: transpose [b,t,f] -> ws[b*32+f][t] (coalesced both sides via LDS tile).
// K1: one wave (64 lanes) per series; 16 elements/lane in registers.
//     Streaming stats + wave butterfly reductions + in-register bitonic sort
//     (lane-major index m = lane*16 + r) for exact ranks 256/512/767.

#define BB 512
#define TT 1024
#define FF 32

// ---------------- K0: transpose ----------------
__global__ __launch_bounds__(256) void transpose_k(const float* __restrict__ x,
                                                   float* __restrict__ xt) {
  __shared__ float tile[128][33];  // +1 pad: write 2-way (free), read 4-way (1.58x, not the bottleneck)
  const int b   = blockIdx.x >> 3;
  const int t0  = (blockIdx.x & 7) << 7;  // 128-row chunk
  const int tid = threadIdx.x;
  const float* src = x + (size_t)b * (TT * FF) + (size_t)t0 * FF;
  // Load: wave covers 8 full 128B rows per instr (fully coalesced).
#pragma unroll
  for (int it = 0; it < 4; ++it) {
    int row = it * 32 + (tid >> 3);
    int fc  = (tid & 7) << 2;
    float4 v = *(const float4*)(src + row * FF + fc);
    tile[row][fc + 0] = v.x; tile[row][fc + 1] = v.y;
    tile[row][fc + 2] = v.z; tile[row][fc + 3] = v.w;
  }
  __syncthreads();
  // Store: per instr a wave writes 2 series x 512B contiguous (fully coalesced).
  const int f8 = tid >> 5;  // 0..7
  const int j  = tid & 31;  // 0..31 -> t offset j*4
#pragma unroll
  for (int ff = 0; ff < 4; ++ff) {
    int f  = ff * 8 + f8;
    int tt = j << 2;
    float4 v;
    v.x = tile[tt + 0][f]; v.y = tile[tt + 1][f];
    v.z = tile[tt + 2][f]; v.w = tile[tt + 3][f];
    *(float4*)(xt + (size_t)(b * FF + f) * TT + t0 + tt) = v;
  }
}

// ---------------- wave reductions ----------------
__device__ __forceinline__ float wsum(float v) {
#pragma unroll
  for (int m = 1; m < 64; m <<= 1) v += __shfl_xor(v, m);
  return v;
}
__device__ __forceinline__ float wmin(float v) {
#pragma unroll
  for (int m = 1; m < 64; m <<= 1) v = fminf(v, __shfl_xor(v, m));
  return v;
}
__device__ __forceinline__ float wmax(float v) {
#pragma unroll
  for (int m = 1; m < 64; m <<= 1) v = fmaxf(v, __shfl_xor(v, m));
  return v;
}

// ---------------- bitonic helpers (all indices compile-time after unroll) ----
__device__ __forceinline__ void ce(float& a, float& b, bool up) {
  float lo = fminf(a, b), hi = fmaxf(a, b);
  a = up ? lo : hi;
  b = up ? hi : lo;
}

// Full bitonic sort of 16 in-lane elements, direction asc.
__device__ __forceinline__ void sort16(float (&d)[16], bool asc) {
#pragma unroll
  for (int kk = 2; kk <= 16; kk <<= 1) {
#pragma unroll
    for (int j = kk >> 1; j >= 1; j >>= 1) {
#pragma unroll
      for (int r = 0; r < 16; ++r) {
        int p = r ^ j;
        if (p > r) {
          bool up = (((r & kk) == 0) == asc);
          ce(d[r], d[p], up);
        }
      }
    }
  }
}

// Bitonic merge of 16 in-lane elements (j = 8..1), direction up.
__device__ __forceinline__ void merge16(float (&d)[16], bool up) {
#pragma unroll
  for (int j = 8; j >= 1; j >>= 1) {
#pragma unroll
    for (int r = 0; r < 16; ++r) {
      int p = r ^ j;
      if (p > r) ce(d[r], d[p], up);
    }
  }
}

// ---------------- K1: per-wave feature extraction ----------------
__global__ __launch_bounds__(256) void feat_k(const float* __restrict__ xt,
                                              float* __restrict__ out) {
  const int wave = (blockIdx.x << 2) + (threadIdx.x >> 6);  // series id 0..16383
  const int lane = threadIdx.x & 63;
  const float* p = xt + (size_t)wave * TT;

  // Load: element e = q*256 + lane*4 + i lives in d[q*4+i]. Fully coalesced.
  float d[16];
#pragma unroll
  for (int q = 0; q < 4; ++q) {
    float4 v = *(const float4*)(p + q * 256 + lane * 4);
    d[q * 4 + 0] = v.x; d[q * 4 + 1] = v.y;
    d[q * 4 + 2] = v.z; d[q * 4 + 3] = v.w;
  }

  // tb values at t = 0, 256, 512, 767, 1023 (known lane/reg slots).
  float tb0 = __shfl(d[0], 0);
  float tb1 = __shfl(d[4], 0);
  float tb2 = __shfl(d[8], 0);
  float tb3 = __shfl(d[11], 63);
  float tb4 = __shfl(d[15], 63);

  // Per-lane streaming stats.
  float s1 = 0.f, s2 = 0.f, s3 = 0.f, s4 = 0.f;
  float mn = d[0], mx = d[0];
  float cpos = 0.f, c0 = 0.f, c1 = 0.f, c2 = 0.f, c3 = 0.f, c4 = 0.f;
#pragma unroll
  for (int r = 0; r < 16; ++r) {
    float v = d[r], v2 = v * v;
    s1 += v; s2 += v2; s3 += v2 * v; s4 += v2 * v2;
    mn = fminf(mn, v); mx = fmaxf(mx, v);
    cpos += (v > 0.f) ? 1.f : 0.f;
    c0 += (v > tb0) ? 1.f : 0.f;
    c1 += (v > tb1) ? 1.f : 0.f;
    c2 += (v > tb2) ? 1.f : 0.f;
    c3 += (v > tb3) ? 1.f : 0.f;
    c4 += (v > tb4) ? 1.f : 0.f;
  }

  // Diffs: d_t = x[t] - x[t+1] for t in [1, 1022].
  float sd = 0.f, sad = 0.f, sdd = 0.f;
#pragma unroll
  for (int q = 0; q < 4; ++q) {
    float nxt = __shfl(d[q * 4], (lane + 1) & 63);        // lane l gets elem q*256+(l+1)*4
    float fix = __shfl(d[((q + 1) & 3) * 4], 0);          // elem (q+1)*256 (lane 63's neighbor)
    if (lane == 63) nxt = fix;                            // q=3 case is masked (t=1023)
#pragma unroll
    for (int i = 0; i < 4; ++i) {
      int t = q * 256 + lane * 4 + i;
      float xn = (i < 3) ? d[q * 4 + i + 1] : nxt;
      float dv = d[q * 4 + i] - xn;
      if (t >= 1 && t <= 1022) { sd += dv; sad += fabsf(dv); sdd += dv * dv; }
    }
  }

  // Reductions (butterfly: every lane gets the total).
  s1 = wsum(s1);
  float mean = s1 * (1.0f / 1024.0f);
  float cm = 0.f;
#pragma unroll
  for (int r = 0; r < 16; ++r) cm += (d[r] > mean) ? 1.f : 0.f;
  s2 = wsum(s2); s3 = wsum(s3); s4 = wsum(s4);
  mn = wmin(mn); mx = wmax(mx);
  sd = wsum(sd); sad = wsum(sad); sdd = wsum(sdd);
  cpos = wsum(cpos); cm = wsum(cm);
  c0 = wsum(c0); c1 = wsum(c1); c2 = wsum(c2); c3 = wsum(c3); c4 = wsum(c4);

  // ---- Sort: bitonic over m = lane*16 + r. Initial data placement is
  // irrelevant for a sort; only the final labeling matters. ----
  sort16(d, (lane & 1) == 0);  // stages k=2..16 (k=16 dir = ((m&16)==0) = lane parity)
#pragma unroll
  for (int kl = 2; kl <= 64; kl <<= 1) {  // k = 16*kl = 32..1024
#pragma unroll
    for (int jl = kl >> 1; jl >= 1; jl >>= 1) {  // cross-lane passes (j = 16*jl)
      bool dir   = (lane & kl) == 0;
      bool lower = (lane & jl) == 0;
      bool tmin  = (dir == lower);
#pragma unroll
      for (int r = 0; r < 16; ++r) {
        float v = __shfl_xor(d[r], jl);
        d[r] = tmin ? fminf(d[r], v) : fmaxf(d[r], v);
      }
    }
    merge16(d, (lane & kl) == 0);  // in-lane j = 8..1
  }
  // Ranks: m=256 -> lane16 r0; m=512 -> lane32 r0; m=767 -> lane47 r15.
  float q1 = __shfl(d[0], 16);
  float q2 = __shfl(d[0], 32);
  float q3 = __shfl(d[15], 47);

  if (lane == 0) {
    const float n = 1024.0f;
    float ex2 = s2 * (1.0f / 1024.0f);
    float rms = (ex2 > 0.f) ? sqrtf(ex2) : 0.f;
    float var = fmaxf(ex2 - mean * mean, 0.f);
    float std = (var > 0.f) ? sqrtf(var) : 0.f;
    float m2  = mean * mean;
    float m3c = s3 - 3.f * mean * s2 + 2048.f * m2 * mean;            // sum (x-m)^3
    float coef3 = (float)(1024.0 / (1023.0 * 1022.0));
    float skew = (std > 0.f) ? coef3 * m3c / (std * std * std) : 0.f;
    float k4c = s4 - 4.f * mean * s3 + 6.f * m2 * s2 - 3072.f * m2 * m2;  // sum (x-m)^4
    float s2c = s2 - n * m2;                                           // sum (x-m)^2
    float k22 = s2c * s2c;
    float alpha = (float)(1024.0 * 1025.0 * 1023.0 / (1022.0 * 1021.0));
    float right = (float)(3.0 * 1023.0 * 1023.0 / (1022.0 * 1021.0));
    float kurt = alpha * ((k22 > 0.f) ? k4c / k22 : 0.f) - right;

    float* o = out + (size_t)wave * 30;
    o[0]  = mean;
    o[1]  = mn;
    o[2]  = mx;
    o[3]  = rms;
    o[4]  = var;
    o[5]  = std;
    o[6]  = skew;
    o[7]  = kurt;
    o[8]  = sd * (1.0f / 1022.0f);
    o[9]  = sd;
    o[10] = sad * (1.0f / 1022.0f);
    o[11] = q1;
    o[12] = q2;
    o[13] = q3;
    o[14] = tb0;
    o[15] = tb1;
    o[16] = tb2;
    o[17] = tb3;
    o[18] = tb4;
    o[19] = s2;
    o[20] = fmaxf(fabsf(mn), fabsf(mx));
    o[21] = sad;
    o[22] = (sdd > 0.f) ? sqrtf(sdd) : 0.f;
    o[23] = cpos;
    o[24] = cm;
    o[25] = c0;
    o[26] = c1;
    o[27] = c2;
    o[28] = c3;
    o[29] = c4;
  }
}

extern "C" void kernel_launch(void* const* d_in, const int* in_sizes, int n_in,
                              void* d_out, int out_size, void* d_ws, size_t ws_size,
                              hipStream_t stream) {
  const float* x = (const float*)d_in[0];
  float* out = (float*)d_out;
  float* xt  = (float*)d_ws;  // needs 512*32*1024*4 = 64 MiB of workspace

  hipLaunchKernelGGL(transpose_k, dim3(4096), dim3(256), 0, stream, x, xt);
  hipLaunchKernelGGL(feat_k, dim3(4096), dim3(256), 0, stream, xt, out);
}

// Round 2
// 165.294 us; speedup vs baseline: 1.1038x; 1.1038x over previous
//
#include <hip/hip_runtime.h>

// ExtractTsFeatures fused: x (512,1024,32) fp32 -> out (512,32,30) fp32.
// One kernel. Block = 256 threads (4 waves) stages 8 series (one b, 8 f's)
// into LDS [8][1028], then each wave computes 2 series entirely in registers:
// 16 elems/lane, element t = q*256 + lane*4 + i in d[q*4+i].
// Cross-lane traffic uses DPP wherever the xor pattern allows (1,2,3,7,8,15),
// ds_swizzle for xor 4/16/31, ds_bpermute for xor 63 / lane+1.
// Exact order stats via always-ascending merge sort (bitonic split+merge).

__device__ __forceinline__ float f_i(int v) { return __int_as_float(v); }
__device__ __forceinline__ int   i_f(float v) { return __float_as_int(v); }

template <int CTRL, bool ZERO>
__device__ __forceinline__ float dppf(float x) {
  int xi = i_f(x);
  return f_i(__builtin_amdgcn_update_dpp(ZERO ? 0 : xi, xi, CTRL, 0xF, 0xF, ZERO));
}

// xor-shuffle: DPP for 1,2,3,7,8,15 (VALU pipe); ds_swizzle for 4,16,31.
template <int MASK>
__device__ __forceinline__ float shx(float x) {
  static_assert(MASK == 1 || MASK == 2 || MASK == 3 || MASK == 4 || MASK == 7 ||
                MASK == 8 || MASK == 15 || MASK == 16 || MASK == 31, "bad mask");
  if constexpr (MASK == 1)  return dppf<0xB1, false>(x);   // quad_perm [1,0,3,2]
  if constexpr (MASK == 2)  return dppf<0x4E, false>(x);   // quad_perm [2,3,0,1]
  if constexpr (MASK == 3)  return dppf<0x1B, false>(x);   // quad_perm [3,2,1,0]
  if constexpr (MASK == 7)  return dppf<0x141, false>(x);  // row_half_mirror
  if constexpr (MASK == 8)  return dppf<0x128, false>(x);  // row_ror:8 == xor 8
  if constexpr (MASK == 15) return dppf<0x140, false>(x);  // row_mirror
  if constexpr (MASK == 4)  return f_i(__builtin_amdgcn_ds_swizzle(i_f(x), 0x101F));
  if constexpr (MASK == 16) return f_i(__builtin_amdgcn_ds_swizzle(i_f(x), 0x401F));
  if constexpr (MASK == 31) return f_i(__builtin_amdgcn_ds_swizzle(i_f(x), 0x7C1F));
  return x;
}

__device__ __forceinline__ float bperm(int addr, float x) {
  return f_i(__builtin_amdgcn_ds_bpermute(addr, i_f(x)));
}
__device__ __forceinline__ float rdl(float v, int l) {
  return f_i(__builtin_amdgcn_readlane(i_f(v), l));
}

// rocPRIM-style DPP reductions; result accumulates at lane 63.
__device__ __forceinline__ float red_sum(float v) {
  v += dppf<0x111, true>(v);   // row_shr:1
  v += dppf<0x112, true>(v);   // row_shr:2
  v += dppf<0x114, true>(v);   // row_shr:4
  v += dppf<0x118, true>(v);   // row_shr:8
  v += dppf<0x142, true>(v);   // row_bcast:15
  v += dppf<0x143, true>(v);   // row_bcast:31
  return rdl(v, 63);
}
__device__ __forceinline__ float red_min(float v) {
  v = fminf(v, dppf<0x111, false>(v));
  v = fminf(v, dppf<0x112, false>(v));
  v = fminf(v, dppf<0x114, false>(v));
  v = fminf(v, dppf<0x118, false>(v));
  v = fminf(v, dppf<0x142, false>(v));
  v = fminf(v, dppf<0x143, false>(v));
  return rdl(v, 63);
}
__device__ __forceinline__ float red_max(float v) {
  v = fmaxf(v, dppf<0x111, false>(v));
  v = fmaxf(v, dppf<0x112, false>(v));
  v = fmaxf(v, dppf<0x114, false>(v));
  v = fmaxf(v, dppf<0x118, false>(v));
  v = fmaxf(v, dppf<0x142, false>(v));
  v = fmaxf(v, dppf<0x143, false>(v));
  return rdl(v, 63);
}

// In-lane ascending bitonic sort of 16 (all directions compile-time).
__device__ __forceinline__ void sort16_asc(float (&d)[16]) {
#pragma unroll
  for (int kk = 2; kk <= 16; kk <<= 1) {
#pragma unroll
    for (int j = kk >> 1; j >= 1; j >>= 1) {
#pragma unroll
      for (int r = 0; r < 16; ++r) {
        int p = r ^ j;
        if (p > r) {
          float lo = fminf(d[r], d[p]);
          float hi = fmaxf(d[r], d[p]);
          bool up = ((r & kk) == 0);  // compile-time after unroll
          d[r] = up ? lo : hi;
          d[p] = up ? hi : lo;
        }
      }
    }
  }
}

// In-lane ascending bitonic merge (j = 8..1).
__device__ __forceinline__ void merge16_asc(float (&d)[16]) {
#pragma unroll
  for (int j = 8; j >= 1; j >>= 1) {
#pragma unroll
    for (int r = 0; r < 16; ++r) {
      int p = r ^ j;
      if (p > r) {
        float lo = fminf(d[r], d[p]);
        d[p] = fmaxf(d[r], d[p]);
        d[r] = lo;
      }
    }
  }
}

// Bitonic split with reversal: pos m pairs with pos N-1-m, i.e. lane^MASK,
// register 15-r. Lower half (lane bit 2^(p-1) clear) keeps min.
template <int MASK>
__device__ __forceinline__ void split_stage(float (&d)[16], int lane) {
  float pv[16];
#pragma unroll
  for (int r = 0; r < 16; ++r) pv[r] = shx<MASK>(d[15 - r]);
  if ((lane & ((MASK + 1) >> 1)) == 0) {
#pragma unroll
    for (int r = 0; r < 16; ++r) d[r] = fminf(d[r], pv[r]);
  } else {
#pragma unroll
    for (int r = 0; r < 16; ++r) d[r] = fmaxf(d[r], pv[r]);
  }
}
__device__ __forceinline__ void split_stage63(float (&d)[16], int lane, int addr63) {
  float pv[16];
#pragma unroll
  for (int r = 0; r < 16; ++r) pv[r] = bperm(addr63, d[15 - r]);
  if ((lane & 32) == 0) {
#pragma unroll
    for (int r = 0; r < 16; ++r) d[r] = fminf(d[r], pv[r]);
  } else {
#pragma unroll
    for (int r = 0; r < 16; ++r) d[r] = fmaxf(d[r], pv[r]);
  }
}

// Straight bitonic-merge stage, lane distance DIST, ascending.
template <int DIST>
__device__ __forceinline__ void xstage(float (&d)[16], int lane) {
  float pv[16];
#pragma unroll
  for (int r = 0; r < 16; ++r) pv[r] = shx<DIST>(d[r]);
  if ((lane & DIST) == 0) {
#pragma unroll
    for (int r = 0; r < 16; ++r) d[r] = fminf(d[r], pv[r]);
  } else {
#pragma unroll
    for (int r = 0; r < 16; ++r) d[r] = fmaxf(d[r], pv[r]);
  }
}

__global__ __launch_bounds__(256, 4) void feat_fused(const float* __restrict__ x,
                                                     float* __restrict__ out) {
  __shared__ __align__(16) float sm[8 * 1028];  // 8 series rows, pad stride 1028
  const int tid  = threadIdx.x;
  const int lane = tid & 63;
  const int wv   = tid >> 6;
  const int g    = blockIdx.x;
  // XCD swizzle: 4 sibling blocks (same b, f8=0..3) land on the same XCD so
  // their 32B sub-line reads hit the same L2. b = (g&7)*64 + (g>>5).
  const int b  = ((g & 7) << 6) + (g >> 5);
  const int f8 = (g >> 3) & 3;

  // ---- stage 8 series into LDS (transposed): sm[row][t], row = f - f8*8 ----
  const float4* xv = (const float4*)x;
  const int fq = tid & 1, t0 = tid >> 1;
  const size_t base4 = (size_t)b * 8192 + (size_t)((f8 << 1) + fq);
#pragma unroll
  for (int it = 0; it < 8; ++it) {
    int t = t0 + (it << 7);
    float4 v = xv[base4 + (size_t)t * 8];
    int row = fq << 2;
    sm[(row + 0) * 1028 + t] = v.x;
    sm[(row + 1) * 1028 + t] = v.y;
    sm[(row + 2) * 1028 + t] = v.z;
    sm[(row + 3) * 1028 + t] = v.w;
  }
  __syncthreads();

  const int addr_nx = ((lane + 1) & 63) << 2;  // bpermute addr: lane+1
  const int addr63  = (lane ^ 63) << 2;        // bpermute addr: lane^63

#pragma unroll 1
  for (int s = 0; s < 2; ++s) {
    const int row = (wv << 1) + s;
    const float* src = &sm[row * 1028];
    float d[16];
#pragma unroll
    for (int q = 0; q < 4; ++q) {
      float4 v = *(const float4*)(src + (q << 8) + (lane << 2));
      d[q * 4 + 0] = v.x; d[q * 4 + 1] = v.y;
      d[q * 4 + 2] = v.z; d[q * 4 + 3] = v.w;
    }

    // tb values at t = 0, 256, 512, 767, 1023 (uniform via readlane)
    float tb0 = rdl(d[0], 0);
    float tb1 = rdl(d[4], 0);
    float tb2 = rdl(d[8], 0);
    float tb3 = rdl(d[11], 63);
    float tb4 = rdl(d[15], 63);

    // raw moments + min/max
    float s1 = 0.f, s2 = 0.f, s3 = 0.f, s4 = 0.f;
    float mn = d[0], mx = d[0];
#pragma unroll
    for (int r = 0; r < 16; ++r) {
      float v = d[r], v2 = v * v;
      s1 += v; s2 += v2;
      s3 = fmaf(v2, v, s3);
      s4 = fmaf(v2, v2, s4);
      mn = fminf(mn, v); mx = fmaxf(mx, v);
    }
    s1 = red_sum(s1);
    float mean = s1 * (1.0f / 1024.0f);

    // counts via ballot+popcount (SALU pipe)
    int cpos = 0, cm = 0, c0 = 0, c1 = 0, c2 = 0, c3 = 0, c4 = 0;
#pragma unroll
    for (int r = 0; r < 16; ++r) {
      float v = d[r];
      cpos += __popcll(__ballot(v > 0.f));
      cm   += __popcll(__ballot(v > mean));
      c0   += __popcll(__ballot(v > tb0));
      c1   += __popcll(__ballot(v > tb1));
      c2   += __popcll(__ballot(v > tb2));
      c3   += __popcll(__ballot(v > tb3));
      c4   += __popcll(__ballot(v > tb4));
    }

    // diffs d_t = x[t]-x[t+1], t in [1,1022]; sum telescopes.
    float j1 = rdl(d[4], 0), j2 = rdl(d[8], 0), j3 = rdl(d[12], 0);
    float x1v = rdl(d[1], 0), x1023 = rdl(d[15], 63);
    bool is63 = (lane == 63), is0 = (lane == 0);
    float sad = 0.f, sdd = 0.f;
#pragma unroll
    for (int q = 0; q < 4; ++q) {
      float nv = bperm(addr_nx, d[q * 4]);  // lane l: elem q*256+(l+1)*4
      if (q == 0) nv = is63 ? j1 : nv;
      if (q == 1) nv = is63 ? j2 : nv;
      if (q == 2) nv = is63 ? j3 : nv;
#pragma unroll
      for (int i = 0; i < 4; ++i) {
        float xn = (i < 3) ? d[q * 4 + i + 1] : nv;
        float dv = d[q * 4 + i] - xn;
        if (q == 0 && i == 0) dv = is0 ? 0.f : dv;   // t=0 excluded
        if (q == 3 && i == 3) dv = is63 ? 0.f : dv;  // t=1023 excluded
        sad += fabsf(dv);
        sdd = fmaf(dv, dv, sdd);
      }
    }
    float SD = x1v - x1023;  // sum of diffs, exact telescope

    s2 = red_sum(s2); s3 = red_sum(s3); s4 = red_sum(s4);
    mn = red_min(mn); mx = red_max(mx);
    sad = red_sum(sad); sdd = red_sum(sdd);

    // ---- exact sort over m = lane*16 + r (ascending merge sort) ----
    sort16_asc(d);
    split_stage<1>(d, lane);
    merge16_asc(d);
    split_stage<3>(d, lane);
    xstage<1>(d, lane);
    merge16_asc(d);
    split_stage<7>(d, lane);
    xstage<2>(d, lane); xstage<1>(d, lane);
    merge16_asc(d);
    split_stage<15>(d, lane);
    xstage<4>(d, lane); xstage<2>(d, lane); xstage<1>(d, lane);
    merge16_asc(d);
    split_stage<31>(d, lane);
    xstage<8>(d, lane); xstage<4>(d, lane); xstage<2>(d, lane); xstage<1>(d, lane);
    merge16_asc(d);
    split_stage63(d, lane, addr63);
    xstage<16>(d, lane); xstage<8>(d, lane); xstage<4>(d, lane);
    xstage<2>(d, lane); xstage<1>(d, lane);
    merge16_asc(d);

    // ranks 256, 512, 767
    float q1v = rdl(d[0], 16), q2v = rdl(d[0], 32), q3v = rdl(d[15], 47);

    if (lane == 0) {
      float ex2 = s2 * (1.0f / 1024.0f);
      float rms = (ex2 > 0.f) ? sqrtf(ex2) : 0.f;
      float var = fmaxf(ex2 - mean * mean, 0.f);
      float stdv = (var > 0.f) ? sqrtf(var) : 0.f;
      float m2 = mean * mean;
      float m3c = s3 - 3.f * mean * s2 + 2048.f * m2 * mean;  // sum (x-m)^3
      const float coef3 = (float)(1024.0 / (1023.0 * 1022.0));
      float skew = (stdv > 0.f) ? coef3 * m3c / (stdv * stdv * stdv) : 0.f;
      float k4c = s4 - 4.f * mean * s3 + 6.f * m2 * s2 - 3072.f * m2 * m2;  // sum (x-m)^4
      float s2c = s2 - 1024.f * m2;
      float k22 = s2c * s2c;
      const float alpha = (float)(1024.0 * 1025.0 * 1023.0 / (1022.0 * 1021.0));
      const float rightc = (float)(3.0 * 1023.0 * 1023.0 / (1022.0 * 1021.0));
      float kurt = alpha * ((k22 > 0.f) ? k4c / k22 : 0.f) - rightc;

      int f = (f8 << 3) + row;
      float* o = out + ((size_t)((b << 5) + f)) * 30;
      o[0] = mean;  o[1] = mn;   o[2] = mx;   o[3] = rms;
      o[4] = var;   o[5] = stdv; o[6] = skew; o[7] = kurt;
      o[8] = SD * (1.0f / 1022.0f);
      o[9] = SD;
      o[10] = sad * (1.0f / 1022.0f);
      o[11] = q1v;  o[12] = q2v; o[13] = q3v;
      o[14] = tb0;  o[15] = tb1; o[16] = tb2; o[17] = tb3; o[18] = tb4;
      o[19] = s2;
      o[20] = fmaxf(fabsf(mn), fabsf(mx));
      o[21] = sad;
      o[22] = (sdd > 0.f) ? sqrtf(sdd) : 0.f;
      o[23] = (float)cpos; o[24] = (float)cm;
      o[25] = (float)c0;   o[26] = (float)c1; o[27] = (float)c2;
      o[28] = (float)c3;   o[29] = (float)c4;
    }
  }
}

extern "C" void kernel_launch(void* const* d_in, const int* in_sizes, int n_in,
                              void* d_out, int out_size, void* d_ws, size_t ws_size,
                              hipStream_t stream) {
  const float* x = (const float*)d_in[0];
  float* out = (float*)d_out;
  hipLaunchKernelGGL(feat_fused, dim3(2048), dim3(256), 0, stream, x, out);
}

// Round 3
// 136.148 us; speedup vs baseline: 1.3401x; 1.2141x over previous
//
#include <hip/hip_runtime.h>

// ExtractTsFeatures fused: x (512,1024,32) fp32 -> out (512,32,30) fp32.
// Block = 256 threads stages 8 series into swizzled LDS (32768 B -> 5 blocks/CU),
// each wave computes 2 series in registers (16 elems/lane, t = q*256+lane*4+i).
// Sort: ascending bitonic merge over m = lane*16 + r. Cross-lane exchanges:
// DPP (masks 1,2,3,7,15) / ds_swizzle (4,8,16,31) / bpermute (63).
// Compare-exchange = 1 exchange + 1 v_med3_f32 with per-lane +-INF limit
// (med3(a,b,+INF)=max, med3(a,b,-INF)=min) -- branchless, 2 VALU/elem.
// Final 1024-merge pruned: after split63+x16, ranks 256/512/767 are group
// extremes of 16-lane blocks -> per-lane min/max + row-16 DPP reduction.

__device__ __forceinline__ float f_i(int v) { return __int_as_float(v); }
__device__ __forceinline__ int   i_f(float v) { return __float_as_int(v); }

template <int CTRL, bool ZERO>
__device__ __forceinline__ float dppf(float x) {
  int xi = i_f(x);
  return f_i(__builtin_amdgcn_update_dpp(ZERO ? 0 : xi, xi, CTRL, 0xF, 0xF, ZERO));
}
template <int CTRL>
__device__ __forceinline__ float dpp0(float x) {
  return f_i(__builtin_amdgcn_update_dpp(0, i_f(x), CTRL, 0xF, 0xF, true));
}

// xor-exchange: DPP for 1,2,3,7,15 (VALU); ds_swizzle for 4,8,16,31 (LDS pipe).
template <int MASK>
__device__ __forceinline__ float ex(float x) {
  static_assert(MASK == 1 || MASK == 2 || MASK == 3 || MASK == 4 || MASK == 7 ||
                MASK == 8 || MASK == 15 || MASK == 16 || MASK == 31, "bad mask");
  if constexpr (MASK == 1)  return dpp0<0xB1>(x);    // quad_perm [1,0,3,2]
  if constexpr (MASK == 2)  return dpp0<0x4E>(x);    // quad_perm [2,3,0,1]
  if constexpr (MASK == 3)  return dpp0<0x1B>(x);    // quad_perm [3,2,1,0]
  if constexpr (MASK == 7)  return dpp0<0x141>(x);   // row_half_mirror
  if constexpr (MASK == 15) return dpp0<0x140>(x);   // row_mirror
  if constexpr (MASK == 4)  return f_i(__builtin_amdgcn_ds_swizzle(i_f(x), 0x101F));
  if constexpr (MASK == 8)  return f_i(__builtin_amdgcn_ds_swizzle(i_f(x), 0x201F));
  if constexpr (MASK == 16) return f_i(__builtin_amdgcn_ds_swizzle(i_f(x), 0x401F));
  if constexpr (MASK == 31) return f_i(__builtin_amdgcn_ds_swizzle(i_f(x), 0x7C1F));
  return x;
}

__device__ __forceinline__ float bperm(int addr, float x) {
  return f_i(__builtin_amdgcn_ds_bpermute(addr, i_f(x)));
}
__device__ __forceinline__ float rdl(float v, int l) {
  return f_i(__builtin_amdgcn_readlane(i_f(v), l));
}
__device__ __forceinline__ float med3(float a, float b, float c) {
  return __builtin_amdgcn_fmed3f(a, b, c);
}

// DPP reductions; result valid at lane 63.
__device__ __forceinline__ float red_sum(float v) {
  v += dppf<0x111, true>(v);   // row_shr:1
  v += dppf<0x112, true>(v);   // row_shr:2
  v += dppf<0x114, true>(v);   // row_shr:4
  v += dppf<0x118, true>(v);   // row_shr:8
  v += dppf<0x142, true>(v);   // row_bcast:15
  v += dppf<0x143, true>(v);   // row_bcast:31
  return rdl(v, 63);
}
__device__ __forceinline__ float red_min(float v) {
  v = fminf(v, dppf<0x111, false>(v));
  v = fminf(v, dppf<0x112, false>(v));
  v = fminf(v, dppf<0x114, false>(v));
  v = fminf(v, dppf<0x118, false>(v));
  v = fminf(v, dppf<0x142, false>(v));
  v = fminf(v, dppf<0x143, false>(v));
  return rdl(v, 63);
}
__device__ __forceinline__ float red_max(float v) {
  v = fmaxf(v, dppf<0x111, false>(v));
  v = fmaxf(v, dppf<0x112, false>(v));
  v = fmaxf(v, dppf<0x114, false>(v));
  v = fmaxf(v, dppf<0x118, false>(v));
  v = fmaxf(v, dppf<0x142, false>(v));
  v = fmaxf(v, dppf<0x143, false>(v));
  return rdl(v, 63);
}

// In-lane ascending bitonic sort of 16.
__device__ __forceinline__ void sort16_asc(float (&d)[16]) {
#pragma unroll
  for (int kk = 2; kk <= 16; kk <<= 1) {
#pragma unroll
    for (int j = kk >> 1; j >= 1; j >>= 1) {
#pragma unroll
      for (int r = 0; r < 16; ++r) {
        int p = r ^ j;
        if (p > r) {
          float lo = fminf(d[r], d[p]);
          float hi = fmaxf(d[r], d[p]);
          bool up = ((r & kk) == 0);
          d[r] = up ? lo : hi;
          d[p] = up ? hi : lo;
        }
      }
    }
  }
}
// In-lane ascending bitonic merge (j = 8..1).
__device__ __forceinline__ void merge16_asc(float (&d)[16]) {
#pragma unroll
  for (int j = 8; j >= 1; j >>= 1) {
#pragma unroll
    for (int r = 0; r < 16; ++r) {
      int p = r ^ j;
      if (p > r) {
        float lo = fminf(d[r], d[p]);
        d[p] = fmaxf(d[r], d[p]);
        d[r] = lo;
      }
    }
  }
}

// Split with reversal: pos m pairs with lane^MASK, reg 15-r. lim = +-INF per lane.
template <int MASK>
__device__ __forceinline__ void split(float (&d)[16], float lim) {
#pragma unroll
  for (int r = 0; r < 8; ++r) {
    float pa = ex<MASK>(d[15 - r]);
    float pb = ex<MASK>(d[r]);
    d[r]      = med3(d[r], pa, lim);
    d[15 - r] = med3(d[15 - r], pb, lim);
  }
}
__device__ __forceinline__ void split63(float (&d)[16], float lim, int addr63) {
#pragma unroll
  for (int r = 0; r < 8; ++r) {
    float pa = bperm(addr63, d[15 - r]);
    float pb = bperm(addr63, d[r]);
    d[r]      = med3(d[r], pa, lim);
    d[15 - r] = med3(d[15 - r], pb, lim);
  }
}
// Straight merge stage at lane distance MASK.
template <int MASK>
__device__ __forceinline__ void xst(float (&d)[16], float lim) {
#pragma unroll
  for (int r = 0; r < 16; ++r) d[r] = med3(d[r], ex<MASK>(d[r]), lim);
}

// Swizzled LDS: 8 rows x 1024, bank offset 4 per row; exactly 32 KiB.
#define SMA(row, t) (((row) << 10) + (((t) + ((row) << 2)) & 1023))

__global__ __launch_bounds__(256, 5) void feat_fused(const float* __restrict__ x,
                                                     float* __restrict__ out) {
  __shared__ __align__(16) float sm[8 * 1024];
  const int tid  = threadIdx.x;
  const int lane = tid & 63;
  const int wv   = tid >> 6;
  const int g    = blockIdx.x;
  const int b  = ((g & 7) << 6) + (g >> 5);   // XCD swizzle: siblings share L2
  const int f8 = (g >> 3) & 3;

  // ---- stage 8 series into LDS (transposed) ----
  const float4* xv = (const float4*)x;
  const int fq = tid & 1, t0 = tid >> 1;
  const size_t base4 = (size_t)b * 8192 + (size_t)((f8 << 1) + fq);
#pragma unroll
  for (int it = 0; it < 8; ++it) {
    int t = t0 + (it << 7);
    float4 v = xv[base4 + (size_t)t * 8];
    int row = fq << 2;
    sm[SMA(row + 0, t)] = v.x;
    sm[SMA(row + 1, t)] = v.y;
    sm[SMA(row + 2, t)] = v.z;
    sm[SMA(row + 3, t)] = v.w;
  }
  __syncthreads();

  const int addr_nx = ((lane + 1) & 63) << 2;
  const int addr63  = (lane ^ 63) << 2;
  const float INF = __builtin_inff();
  // per-lane min/max limits for med3 CEs (computed once)
  const float lim1  = (lane & 1)  ? INF : -INF;
  const float lim2  = (lane & 2)  ? INF : -INF;
  const float lim4  = (lane & 4)  ? INF : -INF;
  const float lim8  = (lane & 8)  ? INF : -INF;
  const float lim16 = (lane & 16) ? INF : -INF;
  const float lim32 = (lane & 32) ? INF : -INF;

#pragma unroll 1
  for (int s = 0; s < 2; ++s) {
    const int row = (wv << 1) + s;
    float d[16];
#pragma unroll
    for (int q = 0; q < 4; ++q) {
      float4 v = *(const float4*)(sm + SMA(row, (q << 8) + (lane << 2)));
      d[q * 4 + 0] = v.x; d[q * 4 + 1] = v.y;
      d[q * 4 + 2] = v.z; d[q * 4 + 3] = v.w;
    }

    // tb values at t = 0, 256, 512, 767, 1023
    float tb0 = rdl(d[0], 0);
    float tb1 = rdl(d[4], 0);
    float tb2 = rdl(d[8], 0);
    float tb3 = rdl(d[11], 63);
    float tb4 = rdl(d[15], 63);

    // raw moments + min/max
    float s1 = 0.f, s2 = 0.f, s3 = 0.f, s4 = 0.f;
    float mn = d[0], mx = d[0];
#pragma unroll
    for (int r = 0; r < 16; ++r) {
      float v = d[r], v2 = v * v;
      s1 += v; s2 += v2;
      s3 = fmaf(v2, v, s3);
      s4 = fmaf(v2, v2, s4);
      mn = fminf(mn, v); mx = fmaxf(mx, v);
    }
    s1 = red_sum(s1);
    float mean = s1 * (1.0f / 1024.0f);

    // counts via ballot+popcount
    int cpos = 0, cm = 0, c0 = 0, c1 = 0, c2 = 0, c3 = 0, c4 = 0;
#pragma unroll
    for (int r = 0; r < 16; ++r) {
      float v = d[r];
      cpos += __popcll(__ballot(v > 0.f));
      cm   += __popcll(__ballot(v > mean));
      c0   += __popcll(__ballot(v > tb0));
      c1   += __popcll(__ballot(v > tb1));
      c2   += __popcll(__ballot(v > tb2));
      c3   += __popcll(__ballot(v > tb3));
      c4   += __popcll(__ballot(v > tb4));
    }

    // diffs d_t = x[t]-x[t+1], t in [1,1022]
    float j1 = rdl(d[4], 0), j2 = rdl(d[8], 0), j3 = rdl(d[12], 0);
    float x1v = rdl(d[1], 0), x1023 = rdl(d[15], 63);
    bool is63 = (lane == 63), is0 = (lane == 0);
    float sad = 0.f, sdd = 0.f;
#pragma unroll
    for (int q = 0; q < 4; ++q) {
      float nv = bperm(addr_nx, d[q * 4]);
      if (q == 0) nv = is63 ? j1 : nv;
      if (q == 1) nv = is63 ? j2 : nv;
      if (q == 2) nv = is63 ? j3 : nv;
#pragma unroll
      for (int i = 0; i < 4; ++i) {
        float xn = (i < 3) ? d[q * 4 + i + 1] : nv;
        float dv = d[q * 4 + i] - xn;
        if (q == 0 && i == 0) dv = is0 ? 0.f : dv;
        if (q == 3 && i == 3) dv = is63 ? 0.f : dv;
        sad += fabsf(dv);
        sdd = fmaf(dv, dv, sdd);
      }
    }
    float SD = x1v - x1023;  // telescoped sum of diffs

    s2 = red_sum(s2); s3 = red_sum(s3); s4 = red_sum(s4);
    mn = red_min(mn); mx = red_max(mx);
    sad = red_sum(sad); sdd = red_sum(sdd);

    // ---- bitonic merge sort over m = lane*16 + r ----
    sort16_asc(d);
    split<1>(d, lim1);  merge16_asc(d);
    split<3>(d, lim2);  xst<1>(d, lim1); merge16_asc(d);
    split<7>(d, lim4);  xst<2>(d, lim2); xst<1>(d, lim1); merge16_asc(d);
    split<15>(d, lim8); xst<4>(d, lim4); xst<2>(d, lim2); xst<1>(d, lim1);
    merge16_asc(d);
    split<31>(d, lim16); xst<8>(d, lim8); xst<4>(d, lim4); xst<2>(d, lim2);
    xst<1>(d, lim1); merge16_asc(d);
    split63(d, lim32, addr63);
    xst<16>(d, lim16);
    // Pruned tail: 16-lane groups are rank-partitioned bitonic blocks.
    // lanes 16..31 hold ranks 256..511; lanes 32..47 hold 512..767.
    float mnv = d[0], mxv = d[0];
#pragma unroll
    for (int r = 1; r < 16; ++r) { mnv = fminf(mnv, d[r]); mxv = fmaxf(mxv, d[r]); }
    mnv = fminf(mnv, ex<1>(mnv)); mxv = fmaxf(mxv, ex<1>(mxv));
    mnv = fminf(mnv, ex<2>(mnv)); mxv = fmaxf(mxv, ex<2>(mxv));
    mnv = fminf(mnv, ex<4>(mnv)); mxv = fmaxf(mxv, ex<4>(mxv));
    mnv = fminf(mnv, ex<8>(mnv)); mxv = fmaxf(mxv, ex<8>(mxv));
    float q1v = rdl(mnv, 16);  // rank 256
    float q2v = rdl(mnv, 32);  // rank 512
    float q3v = rdl(mxv, 32);  // rank 767

    if (lane == 0) {
      float ex2 = s2 * (1.0f / 1024.0f);
      float rms = (ex2 > 0.f) ? sqrtf(ex2) : 0.f;
      float var = fmaxf(ex2 - mean * mean, 0.f);
      float stdv = (var > 0.f) ? sqrtf(var) : 0.f;
      float m2 = mean * mean;
      float m3c = s3 - 3.f * mean * s2 + 2048.f * m2 * mean;
      const float coef3 = (float)(1024.0 / (1023.0 * 1022.0));
      float skew = (stdv > 0.f) ? coef3 * m3c / (stdv * stdv * stdv) : 0.f;
      float k4c = s4 - 4.f * mean * s3 + 6.f * m2 * s2 - 3072.f * m2 * m2;
      float s2c = s2 - 1024.f * m2;
      float k22 = s2c * s2c;
      const float alpha = (float)(1024.0 * 1025.0 * 1023.0 / (1022.0 * 1021.0));
      const float rightc = (float)(3.0 * 1023.0 * 1023.0 / (1022.0 * 1021.0));
      float kurt = alpha * ((k22 > 0.f) ? k4c / k22 : 0.f) - rightc;

      int f = (f8 << 3) + row;
      float* o = out + ((size_t)((b << 5) + f)) * 30;
      o[0] = mean;  o[1] = mn;   o[2] = mx;   o[3] = rms;
      o[4] = var;   o[5] = stdv; o[6] = skew; o[7] = kurt;
      o[8] = SD * (1.0f / 1022.0f);
      o[9] = SD;
      o[10] = sad * (1.0f / 1022.0f);
      o[11] = q1v;  o[12] = q2v; o[13] = q3v;
      o[14] = tb0;  o[15] = tb1; o[16] = tb2; o[17] = tb3; o[18] = tb4;
      o[19] = s2;
      o[20] = fmaxf(fabsf(mn), fabsf(mx));
      o[21] = sad;
      o[22] = (sdd > 0.f) ? sqrtf(sdd) : 0.f;
      o[23] = (float)cpos; o[24] = (float)cm;
      o[25] = (float)c0;   o[26] = (float)c1; o[27] = (float)c2;
      o[28] = (float)c3;   o[29] = (float)c4;
    }
  }
}

extern "C" void kernel_launch(void* const* d_in, const int* in_sizes, int n_in,
                              void* d_out, int out_size, void* d_ws, size_t ws_size,
                              hipStream_t stream) {
  const float* x = (const float*)d_in[0];
  float* out = (float*)d_out;
  hipLaunchKernelGGL(feat_fused, dim3(2048), dim3(256), 0, stream, x, out);
}